// Round 10
// baseline (1201.831 us; speedup 1.0000x reference)
//
#include <hip/hip_runtime.h>
#include <cstddef>

#define BATCH 32
#define NPTS  1024
#define K_NN  12
#define HID   64
#define BN_EPS 1e-5f

typedef float v2f __attribute__((ext_vector_type(2)));

// ---------------------------------------------------------------------------
// d2[j] = ||x_j||^2 precompute.
// ---------------------------------------------------------------------------
template<int C>
__global__ __launch_bounds__(256) void d2_kernel(const float* __restrict__ x,
                                                 float* __restrict__ d2) {
  int gid = blockIdx.x * 256 + threadIdx.x;          // < B*N
  const float* xp = x + (size_t)gid * C;
  float s;
  if constexpr (C % 4 == 0) {
    const float4* x4 = (const float4*)xp;
    float a0 = 0.f, a1 = 0.f, a2 = 0.f, a3 = 0.f;
#pragma unroll
    for (int q = 0; q < C / 4; ++q) {
      float4 v = x4[q];
      a0 = fmaf(v.x, v.x, a0); a1 = fmaf(v.y, v.y, a1);
      a2 = fmaf(v.z, v.z, a2); a3 = fmaf(v.w, v.w, a3);
    }
    s = (a0 + a1) + (a2 + a3);
  } else {
    s = 0.f;
#pragma unroll
    for (int c = 0; c < C; ++c) { float v = xp[c]; s = fmaf(v, v, s); }
  }
  d2[gid] = s;
}

// ---------------------------------------------------------------------------
// kNN part v10: R9's proven inner loop (pk_fma dot, exact (d,j) insert,
// wave-uniform j via readfirstlane), restructured for occupancy: 256-thread
// blocks (4 waves x 64-j slices), grid.z = 4 j-quadrants -> 2048 blocks,
// LDS merge arrays halve to 24.5 KB -> 6 blocks/CU (was 2-3). Block merges
// its 4 slices; cross-quadrant merge in knn_merge_kernel.
// ---------------------------------------------------------------------------
template<int C>
__global__ __launch_bounds__(256, 2) void knn_part_kernel(
    const float* __restrict__ x, const float* __restrict__ d2,
    float* __restrict__ cand_d, int* __restrict__ cand_j) {
  const int b    = blockIdx.y;
  const int lane = threadIdx.x & 63;
  const int wv_u = __builtin_amdgcn_readfirstlane(threadIdx.x >> 6);  // 0..3
  const int i    = blockIdx.x * 64 + lane;
  const float* xb  = x  + (size_t)b * NPTS * C;
  const float* d2b = d2 + (size_t)b * NPTS;

  constexpr int NE = 4 * K_NN;                       // 48 entries/row in block
  __shared__ float lds_d[64][NE + 1];                // stride 49: odd, no confl
  __shared__ int   lds_j[64][NE + 1];

  constexpr int CP = (C % 4 == 0) ? C / 2 : 1;
  v2f   xi2[CP];                                     // C%4==0 path
  float xis[(C % 4 == 0) ? 1 : C];                   // small-C path
  if constexpr (C % 4 == 0) {
    const float4* xr = (const float4*)(xb + (size_t)i * C);
#pragma unroll
    for (int q = 0; q < C / 4; ++q) {
      float4 v = xr[q];
      xi2[2 * q + 0] = v2f{v.x, v.y};
      xi2[2 * q + 1] = v2f{v.z, v.w};
    }
#pragma unroll
    for (int q = 0; q < CP; ++q) asm volatile("" : "+v"(xi2[q]));  // no remat
  } else {
#pragma unroll
    for (int c = 0; c < C; ++c) xis[c] = xb[(size_t)i * C + c];
  }

  float bd[K_NN]; int bj[K_NN];
#pragma unroll
  for (int k = 0; k < K_NN; ++k) { bd[k] = 3.4e38f; bj[k] = 0x7fffffff; }

  const int j0 = blockIdx.z * 256 + wv_u * 64;       // uniform slice base
#pragma unroll 2
  for (int jj = 0; jj < 64; ++jj) {
    const int j = j0 + jj;                           // uniform
    const float* xj = xb + (size_t)j * C;            // uniform -> s_load
    const float d2j = d2b[j];                        // uniform -> s_load
    float dot;
    if constexpr (C % 4 == 0) {
      const v2f* xj2 = (const v2f*)xj;
      v2f a0{0.f, 0.f}, a1{0.f, 0.f}, a2{0.f, 0.f}, a3{0.f, 0.f};
#pragma unroll
      for (int q = 0; q < CP; q += 4) {
        a0 = __builtin_elementwise_fma(xi2[q + 0], xj2[q + 0], a0);
        a1 = __builtin_elementwise_fma(xi2[q + 1], xj2[q + 1], a1);
        a2 = __builtin_elementwise_fma(xi2[q + 2], xj2[q + 2], a2);
        a3 = __builtin_elementwise_fma(xi2[q + 3], xj2[q + 3], a3);
      }
      v2f as = (a0 + a1) + (a2 + a3);
      dot = as.x + as.y;
    } else {
      dot = 0.f;
#pragma unroll
      for (int c = 0; c < C; ++c) dot = fmaf(xis[c], xj[c], dot);
    }
    // d2_i (row-constant) dropped: doesn't change per-row top-k order.
    const float dval = fmaf(-2.f, dot, d2j);
    if (dval < bd[K_NN - 1]) {                       // strict <: scanning j
      float dk = dval; int jk = j;                   // ascending keeps lower j
#pragma unroll
      for (int s = 0; s < K_NN; ++s) {               // exact branchless insert
        bool sw = dk < bd[s];
        float nd = fminf(dk, bd[s]);
        float xd = fmaxf(dk, bd[s]);
        int nj = sw ? jk : bj[s];
        int xjj = sw ? bj[s] : jk;
        bd[s] = nd; bj[s] = nj; dk = xd; jk = xjj;
      }
    }
  }

#pragma unroll
  for (int k = 0; k < K_NN; ++k) {
    lds_d[lane][wv_u * K_NN + k] = bd[k];
    lds_j[lane][wv_u * K_NN + k] = bj[k];
  }
  __syncthreads();

  if (wv_u == 0) {                                   // merge block's 4 slices
    float md[K_NN]; int mj[K_NN];
#pragma unroll
    for (int k = 0; k < K_NN; ++k) { md[k] = 3.4e38f; mj[k] = 0x7fffffff; }
    for (int e = 0; e < NE; ++e) {                   // ascending slice order
      float dk = lds_d[lane][e]; int jk = lds_j[lane][e];
      if (dk < md[K_NN - 1]) {
#pragma unroll
        for (int s = 0; s < K_NN; ++s) {
          bool sw = dk < md[s];
          float nd = fminf(dk, md[s]);
          float xd = fmaxf(dk, md[s]);
          int nj = sw ? jk : mj[s];
          int xjj = sw ? mj[s] : jk;
          md[s] = nd; mj[s] = nj; dk = xd; jk = xjj;
        }
      }
    }
    const size_t row = (size_t)b * NPTS + blockIdx.x * 64 + lane;
    float* cd = cand_d + (row * 4 + blockIdx.z) * K_NN;
    int*   cj = cand_j + (row * 4 + blockIdx.z) * K_NN;
#pragma unroll
    for (int k = 0; k < K_NN; ++k) { cd[k] = md[k]; cj[k] = mj[k]; }
  }
}

// ---------------------------------------------------------------------------
// knn merge: 4 quadrant lists of 12 -> final 12. Quadrants cover ascending
// j-ranges and lists are (d,j)-lexicographically stable, so scanning in
// order with strict < keeps the lower j on ties (= jax.lax.top_k).
// ---------------------------------------------------------------------------
__global__ __launch_bounds__(256) void knn_merge_kernel(
    const float* __restrict__ cand_d, const int* __restrict__ cand_j,
    int* __restrict__ idx) {
  const int row = blockIdx.x * 256 + threadIdx.x;    // 0..32767
  const float* cd = cand_d + (size_t)row * (4 * K_NN);
  const int*   cj = cand_j + (size_t)row * (4 * K_NN);
  float md[K_NN]; int mj[K_NN];
#pragma unroll
  for (int k = 0; k < K_NN; ++k) { md[k] = 3.4e38f; mj[k] = 0x7fffffff; }
#pragma unroll 4
  for (int e = 0; e < 4 * K_NN; ++e) {
    float dk = cd[e]; int jk = cj[e];
    if (dk < md[K_NN - 1]) {
#pragma unroll
      for (int s = 0; s < K_NN; ++s) {
        bool sw = dk < md[s];
        float nd = fminf(dk, md[s]);
        float xd = fmaxf(dk, md[s]);
        int nj = sw ? jk : mj[s];
        int xjj = sw ? mj[s] : jk;
        md[s] = nd; mj[s] = nj; dk = xd; jk = xjj;
      }
    }
  }
  int* op = idx + (size_t)row * K_NN;
#pragma unroll
  for (int k = 0; k < K_NN; ++k) op[k] = mj[k];
}

// ---------------------------------------------------------------------------
// wprep: W1c = W1a - W1b for all 4 layers.
// ---------------------------------------------------------------------------
__global__ __launch_bounds__(256) void wprep_kernel(const float* __restrict__ wa,
                                                    const float* __restrict__ w0a,
                                                    float* __restrict__ w1c) {
  int t = blockIdx.x * 256 + threadIdx.x;
  if (t < 12288) {
    int i = t >> 12, r = t & 4095;
    w1c[t] = wa[i * 8192 + r] - wa[i * 8192 + 4096 + r];
  } else if (t < 12288 + 192) {
    int r = t - 12288;
    w1c[t] = w0a[r] - w0a[192 + r];
  }
}

// ---------------------------------------------------------------------------
// rowgemm2: dual-output 64x64 rowgemm. YA = biasA + X@WA, YB = X@WB.
// ---------------------------------------------------------------------------
__global__ __launch_bounds__(256) void rowgemm2_kernel(
    const float* __restrict__ X, const float* __restrict__ WA,
    const float* __restrict__ biasA, const float* __restrict__ WB,
    float* __restrict__ YA, float* __restrict__ YB) {
  __shared__ float wsa[HID * HID];
  __shared__ float wsb[HID * HID];
  for (int t = threadIdx.x; t < HID * HID; t += 256) { wsa[t] = WA[t]; wsb[t] = WB[t]; }
  __syncthreads();

  const int lane = threadIdx.x & 63;
  const int wv   = threadIdx.x >> 6;
  const int fq   = lane & 15;
  const int rg   = lane >> 4;
  const int r0   = blockIdx.x * 32 + wv * 8 + rg * 2;

  const float4* X4 = (const float4*)X;
  const float4* WA4 = (const float4*)wsa;
  const float4* WB4 = (const float4*)wsb;
  float aA0[4] = {0,0,0,0}, aA1[4] = {0,0,0,0};
  float aB0[4] = {0,0,0,0}, aB1[4] = {0,0,0,0};

#pragma unroll 2
  for (int cq = 0; cq < 16; ++cq) {
    float4 xa = X4[(size_t)r0 * 16 + cq];
    float4 xb_ = X4[(size_t)(r0 + 1) * 16 + cq];
    float ea[4] = {xa.x, xa.y, xa.z, xa.w};
    float eb[4] = {xb_.x, xb_.y, xb_.z, xb_.w};
#pragma unroll
    for (int d = 0; d < 4; ++d) {
      float4 wa4 = WA4[(cq * 4 + d) * 16 + fq];
      float4 wb4 = WB4[(cq * 4 + d) * 16 + fq];
      float wA[4] = {wa4.x, wa4.y, wa4.z, wa4.w};
      float wB[4] = {wb4.x, wb4.y, wb4.z, wb4.w};
#pragma unroll
      for (int k = 0; k < 4; ++k) {
        aA0[k] = fmaf(ea[d], wA[k], aA0[k]);
        aA1[k] = fmaf(eb[d], wA[k], aA1[k]);
        aB0[k] = fmaf(ea[d], wB[k], aB0[k]);
        aB1[k] = fmaf(eb[d], wB[k], aB1[k]);
      }
    }
  }
  float4 b4 = ((const float4*)biasA)[fq];
  float4 oA0{aA0[0] + b4.x, aA0[1] + b4.y, aA0[2] + b4.z, aA0[3] + b4.w};
  float4 oA1{aA1[0] + b4.x, aA1[1] + b4.y, aA1[2] + b4.z, aA1[3] + b4.w};
  float4 oB0{aB0[0], aB0[1], aB0[2], aB0[3]};
  float4 oB1{aB1[0], aB1[1], aB1[2], aB1[3]};
  ((float4*)YA)[(size_t)r0 * 16 + fq] = oA0;
  ((float4*)YA)[(size_t)(r0 + 1) * 16 + fq] = oA1;
  ((float4*)YB)[(size_t)r0 * 16 + fq] = oB0;
  ((float4*)YB)[(size_t)(r0 + 1) * 16 + fq] = oB1;
}

// ---------------------------------------------------------------------------
// dual3: layer-0 projections (C=3). hxi = x@(A-B) + b1, hxj = x@B.
// ---------------------------------------------------------------------------
__global__ __launch_bounds__(256) void dual3_kernel(
    const float* __restrict__ x, const float* __restrict__ w1c0,
    const float* __restrict__ w0a, const float* __restrict__ b1,
    float* __restrict__ hxi, float* __restrict__ hxj) {
  __shared__ float Cs[3 * HID], Bs[3 * HID], bs[HID];
  for (int t = threadIdx.x; t < 3 * HID; t += 256) {
    Cs[t] = w1c0[t];
    Bs[t] = w0a[192 + t];
  }
  if (threadIdx.x < HID) bs[threadIdx.x] = b1[threadIdx.x];
  __syncthreads();

  const int lane = threadIdx.x & 63;
  const int wv   = __builtin_amdgcn_readfirstlane(threadIdx.x >> 6);
  const int node0 = blockIdx.x * 32;
#pragma unroll 1
  for (int it = 0; it < 8; ++it) {
    const int n = node0 + it * 4 + wv;               // uniform
    const float* xr = x + (size_t)n * 3;             // uniform -> s_load
    float x0 = xr[0], x1 = xr[1], x2 = xr[2];
    float hi = bs[lane];
    hi = fmaf(x0, Cs[0 * HID + lane], hi);
    hi = fmaf(x1, Cs[1 * HID + lane], hi);
    hi = fmaf(x2, Cs[2 * HID + lane], hi);
    float hj = x0 * Bs[0 * HID + lane];
    hj = fmaf(x1, Bs[1 * HID + lane], hj);
    hj = fmaf(x2, Bs[2 * HID + lane], hj);
    hxi[(size_t)n * HID + lane] = hi;
    hxj[(size_t)n * HID + lane] = hj;
  }
}

// ---------------------------------------------------------------------------
// egstats: BN sum/sumsq over all edges of h = hxi[n] + hxj[j].
// ---------------------------------------------------------------------------
__global__ __launch_bounds__(256) void egstats_kernel(
    const int* __restrict__ idx, const float* __restrict__ hxi,
    const float* __restrict__ hxj, float* __restrict__ partial) {
  const int lane = threadIdx.x & 63;
  const int wv   = __builtin_amdgcn_readfirstlane(threadIdx.x >> 6);
  const int node0 = blockIdx.x * 32;
  float s1 = 0.f, s2 = 0.f;

#pragma unroll 1
  for (int it = 0; it < 8; ++it) {
    const int n = node0 + it * 4 + wv;               // uniform
    const int bbase = (n >> 10) << 10;               // b*N
    const int* ip = idx + (size_t)n * K_NN;          // uniform -> s_load
    int j[K_NN];
#pragma unroll
    for (int k = 0; k < K_NN; ++k) j[k] = ip[k];
    const float hv = hxi[(size_t)n * HID + lane];
    float v[K_NN];
#pragma unroll
    for (int k = 0; k < K_NN; ++k)                   // 12 independent gathers
      v[k] = hxj[(size_t)(bbase + j[k]) * HID + lane];
#pragma unroll
    for (int k = 0; k < K_NN; ++k) { float h = hv + v[k]; s1 += h; s2 = fmaf(h, h, s2); }
  }

  __shared__ float red[4][HID];
  red[wv][lane] = s1;
  __syncthreads();
  if (threadIdx.x < HID)
    partial[(size_t)blockIdx.x * 128 + lane] =
        (red[0][lane] + red[1][lane]) + (red[2][lane] + red[3][lane]);
  __syncthreads();
  red[wv][lane] = s2;
  __syncthreads();
  if (threadIdx.x < HID)
    partial[(size_t)blockIdx.x * 128 + 64 + lane] =
        (red[0][lane] + red[1][lane]) + (red[2][lane] + red[3][lane]);
}

// ---------------------------------------------------------------------------
// Reduce 1024 block-partials, finalize BN scale/shift into stats[128..255].
// ---------------------------------------------------------------------------
__global__ void bn_reduce_finalize_kernel(const float* __restrict__ g,
                                          const float* __restrict__ be,
                                          const float* __restrict__ partial,
                                          float* __restrict__ stats) {
  int t = threadIdx.x;                               // 0..127
  float a0 = 0.f, a1 = 0.f, a2 = 0.f, a3 = 0.f;
  for (int gb = 0; gb < 1024; gb += 4) {
    a0 += partial[(size_t)(gb + 0) * 128 + t];
    a1 += partial[(size_t)(gb + 1) * 128 + t];
    a2 += partial[(size_t)(gb + 2) * 128 + t];
    a3 += partial[(size_t)(gb + 3) * 128 + t];
  }
  __shared__ float sm[128];
  sm[t] = (a0 + a1) + (a2 + a3);
  __syncthreads();
  if (t < HID) {
    const float inv_n = 1.f / (float)(BATCH * NPTS * K_NN);
    float m = sm[t] * inv_n;
    float v = sm[HID + t] * inv_n - m * m;
    float A = g[t] * rsqrtf(v + BN_EPS);
    stats[128 + t] = A;
    stats[192 + t] = be[t] - m * A;
  }
}

// ---------------------------------------------------------------------------
// egapply_gemm: fused BN-apply + relu + mean-over-K + W2 + b2.
// ---------------------------------------------------------------------------
__global__ __launch_bounds__(256) void egapply_gemm_kernel(
    const int* __restrict__ idx, const float* __restrict__ hxi,
    const float* __restrict__ hxj, const float* __restrict__ stats,
    const float* __restrict__ W2, const float* __restrict__ b2,
    float* __restrict__ out) {
  __shared__ float w2s[HID * HID];
  __shared__ float red[32][HID];
  for (int t = threadIdx.x; t < HID * HID; t += 256) w2s[t] = W2[t];

  const int lane = threadIdx.x & 63;
  const int wv   = __builtin_amdgcn_readfirstlane(threadIdx.x >> 6);
  const int node0 = blockIdx.x * 32;
  const float A = stats[128 + lane], Bc = stats[192 + lane];

#pragma unroll 1
  for (int it = 0; it < 8; ++it) {
    const int n = node0 + it * 4 + wv;               // uniform
    const int bbase = (n >> 10) << 10;
    const int* ip = idx + (size_t)n * K_NN;          // uniform -> s_load
    int j[K_NN];
#pragma unroll
    for (int k = 0; k < K_NN; ++k) j[k] = ip[k];
    const float hv = hxi[(size_t)n * HID + lane];
    float v[K_NN];
#pragma unroll
    for (int k = 0; k < K_NN; ++k)
      v[k] = hxj[(size_t)(bbase + j[k]) * HID + lane];
    float acc = 0.f;
#pragma unroll
    for (int k = 0; k < K_NN; ++k) { float h = hv + v[k]; acc += fmaxf(fmaf(A, h, Bc), 0.f); }
    red[it * 4 + wv][lane] = acc;
  }
  __syncthreads();

  const float b2f = b2[lane];
  const float inv = 1.f / (float)K_NN;
#pragma unroll 2
  for (int p = 0; p < 8; ++p) {
    int r = p * 4 + wv;                              // uniform row
    float acc = 0.f;
#pragma unroll 8
    for (int h = 0; h < HID; ++h) acc = fmaf(red[r][h], w2s[h * HID + lane], acc);
    out[(size_t)(node0 + r) * HID + lane] = fmaf(acc, inv, b2f);
  }
}

// ---------------------------------------------------------------------------
__global__ __launch_bounds__(256) void pool_kernel(const float* __restrict__ h,
                                                   float* __restrict__ pooled) {
  const int b = blockIdx.x;
  const int f = threadIdx.x & 63;
  const int gsz = threadIdx.x >> 6;
  __shared__ float red[4][HID];
  float s = 0.f;
  for (int n = gsz; n < NPTS; n += 4) s += h[((size_t)b * NPTS + n) * HID + f];
  red[gsz][f] = s;
  __syncthreads();
  if (threadIdx.x < HID)
    pooled[b * HID + f] = ((red[0][f] + red[1][f]) + (red[2][f] + red[3][f])) * (1.f / (float)NPTS);
}

__global__ __launch_bounds__(256) void head_kernel(const float* __restrict__ pooled,
    const float* __restrict__ wf1, const float* __restrict__ bf1,
    const float* __restrict__ gf, const float* __restrict__ bef,
    const float* __restrict__ wf2, const float* __restrict__ bf2,
    float* __restrict__ out) {
  __shared__ float pl[BATCH * HID];
  __shared__ float t[BATCH * 32];
  __shared__ float Ab[32], Bb[32];
  for (int i = threadIdx.x; i < BATCH * HID; i += 256) pl[i] = pooled[i];
  __syncthreads();
  for (int i = threadIdx.x; i < BATCH * 32; i += 256) {
    int s = i >> 5, f1 = i & 31;
    float acc = bf1[f1];
    for (int h = 0; h < HID; ++h) acc = fmaf(pl[s * HID + h], wf1[h * 32 + f1], acc);
    t[i] = acc;
  }
  __syncthreads();
  if (threadIdx.x < 32) {
    int f1 = threadIdx.x;
    float m = 0.f;
    for (int s = 0; s < BATCH; ++s) m += t[s * 32 + f1];
    m *= (1.f / (float)BATCH);
    float v = 0.f;
    for (int s = 0; s < BATCH; ++s) { float d = t[s * 32 + f1] - m; v = fmaf(d, d, v); }
    v *= (1.f / (float)BATCH);
    float A = gf[f1] * rsqrtf(v + BN_EPS);
    Ab[f1] = A; Bb[f1] = bef[f1] - m * A;
  }
  __syncthreads();
  for (int i = threadIdx.x; i < BATCH * 32; i += 256) {
    int f1 = i & 31;
    t[i] = fmaxf(fmaf(Ab[f1], t[i], Bb[f1]), 0.f);
  }
  __syncthreads();
  if (threadIdx.x < BATCH * 2) {
    int s = threadIdx.x >> 1, o = threadIdx.x & 1;
    float acc = bf2[o];
    for (int f1 = 0; f1 < 32; ++f1) acc = fmaf(t[s * 32 + f1], wf2[f1 * 2 + o], acc);
    out[s * 2 + o] = acc;
  }
}

// ---------------------------------------------------------------------------
extern "C" void kernel_launch(void* const* d_in, const int* in_sizes, int n_in,
                              void* d_out, int out_size, void* d_ws, size_t ws_size,
                              hipStream_t stream) {
  const float* x   = (const float*)d_in[0];
  const float* w0a = (const float*)d_in[1];
  const float* b0a = (const float*)d_in[2];
  const float* g0  = (const float*)d_in[3];
  const float* be0 = (const float*)d_in[4];
  const float* w0b = (const float*)d_in[5];
  const float* b0b = (const float*)d_in[6];
  const float* wa  = (const float*)d_in[7];
  const float* ba  = (const float*)d_in[8];
  const float* ga  = (const float*)d_in[9];
  const float* bea = (const float*)d_in[10];
  const float* wb  = (const float*)d_in[11];
  const float* bb  = (const float*)d_in[12];
  const float* wf1 = (const float*)d_in[13];
  const float* bf1 = (const float*)d_in[14];
  const float* gf  = (const float*)d_in[15];
  const float* bef = (const float*)d_in[16];
  const float* wf2 = (const float*)d_in[17];
  const float* bf2 = (const float*)d_in[18];

  float* ws = (float*)d_ws;
  const size_t HN = (size_t)BATCH * NPTS * HID;         // 2,097,152
  const size_t ROWS = (size_t)BATCH * NPTS;             // 32768
  float* bufA    = ws;                                  // HN
  float* bufB    = bufA + HN;                           // HN
  float* hxi     = bufB + HN;                           // HN
  float* hxjb    = hxi + HN;                            // HN
  float* w1c     = hxjb + HN;                           // 12544
  int*   idxb    = (int*)(w1c + 12544);                 // ROWS*12
  float* d2buf   = (float*)(idxb + ROWS * K_NN);        // ROWS
  float* stats   = d2buf + ROWS;                        // 256
  float* partial = stats + 256;                         // 1024*128
  float* pooled  = partial + 1024 * 128;                // 2048
  // cand buffers alias hxi/hxjb: per layer, knn_part+merge run BEFORE
  // rowgemm2/dual3 overwrite the region (stream-ordered). 32768*48 <= HN.
  float* cand_d  = hxi;
  int*   cand_j  = (int*)hxjb;

  wprep_kernel<<<49, 256, 0, stream>>>(wa, w0a, w1c);

  // ---- layer 0 (C=3, gather path) ----
  d2_kernel<3><<<(int)(ROWS / 256), 256, 0, stream>>>(x, d2buf);
  knn_part_kernel<3><<<dim3(16, BATCH, 4), 256, 0, stream>>>(x, d2buf, cand_d, cand_j);
  knn_merge_kernel<<<128, 256, 0, stream>>>(cand_d, cand_j, idxb);
  dual3_kernel<<<1024, 256, 0, stream>>>(x, w1c + 12288, w0a, b0a, hxi, hxjb);
  egstats_kernel<<<1024, 256, 0, stream>>>(idxb, hxi, hxjb, partial);
  bn_reduce_finalize_kernel<<<1, 128, 0, stream>>>(g0, be0, partial, stats);
  egapply_gemm_kernel<<<1024, 256, 0, stream>>>(idxb, hxi, hxjb, stats, w0b, b0b, bufA);

  // ---- layers 1..3 (gather path) ----
  const float* cur = bufA;
  float* nxt = bufB;
  for (int i = 0; i < 3; ++i) {
    const float* W1b = wa + (size_t)i * 8192 + 4096;
    d2_kernel<HID><<<(int)(ROWS / 256), 256, 0, stream>>>(cur, d2buf);
    knn_part_kernel<HID><<<dim3(16, BATCH, 4), 256, 0, stream>>>(cur, d2buf, cand_d, cand_j);
    knn_merge_kernel<<<128, 256, 0, stream>>>(cand_d, cand_j, idxb);
    rowgemm2_kernel<<<(int)(ROWS / 32), 256, 0, stream>>>(cur, w1c + (size_t)i * 4096,
                                                          ba + i * HID, W1b, hxi, hxjb);
    egstats_kernel<<<1024, 256, 0, stream>>>(idxb, hxi, hxjb, partial);
    bn_reduce_finalize_kernel<<<1, 128, 0, stream>>>(ga + i * HID, bea + i * HID, partial, stats);
    egapply_gemm_kernel<<<1024, 256, 0, stream>>>(idxb, hxi, hxjb, stats,
                                                  wb + (size_t)i * 4096, bb + i * HID, nxt);
    const float* t = cur; cur = nxt; nxt = (float*)t;
  }

  pool_kernel<<<BATCH, 256, 0, stream>>>(cur, pooled);
  head_kernel<<<1, 256, 0, stream>>>(pooled, wf1, bf1, gf, bef, wf2, bf2, (float*)d_out);
}

// Round 11
// 1044.252 us; speedup vs baseline: 1.1509x; 1.1509x over previous
//
#include <hip/hip_runtime.h>
#include <cstddef>

#define BATCH 32
#define NPTS  1024
#define K_NN  12
#define HID   64
#define BN_EPS 1e-5f

typedef float v2f __attribute__((ext_vector_type(2)));

// ---------------------------------------------------------------------------
// d2[j] = ||x_j||^2 precompute.
// ---------------------------------------------------------------------------
template<int C>
__global__ __launch_bounds__(256) void d2_kernel(const float* __restrict__ x,
                                                 float* __restrict__ d2) {
  int gid = blockIdx.x * 256 + threadIdx.x;          // < B*N
  const float* xp = x + (size_t)gid * C;
  float s;
  if constexpr (C % 4 == 0) {
    const float4* x4 = (const float4*)xp;
    float a0 = 0.f, a1 = 0.f, a2 = 0.f, a3 = 0.f;
#pragma unroll
    for (int q = 0; q < C / 4; ++q) {
      float4 v = x4[q];
      a0 = fmaf(v.x, v.x, a0); a1 = fmaf(v.y, v.y, a1);
      a2 = fmaf(v.z, v.z, a2); a3 = fmaf(v.w, v.w, a3);
    }
    s = (a0 + a1) + (a2 + a3);
  } else {
    s = 0.f;
#pragma unroll
    for (int c = 0; c < C; ++c) { float v = xp[c]; s = fmaf(v, v, s); }
  }
  d2[gid] = s;
}

// ---------------------------------------------------------------------------
// kNN C=64 v11: R9 shape (8 waves x 128-j slices, 512 thr) but NO persistent
// xi array. R10 falsified the LDS-occupancy theory: the cap is registers
// (56 arch + ~64 AGPR-parked xi = ~120/wave -> 4 waves/SIMD). Here xi lives
// in LDS (aliases merge arrays, R8-proven); per 8-j tile: acc[8] (16 VGPR) +
// one 16-v2f xi chunk at a time (32 VGPR, halves separated by unroll 1) ->
// hot set ~85 regs -> 5 waves/SIMD. Per j: 2 ds_read_b128 (24 LDS-cyc,
// stride-68 = phase-minimal, 0 conflicts in R8) vs ~114 VALU-cyc: VALU-bound.
// j wave-uniform (readfirstlane) -> xj/d2j on scalar pipe. Exact (d,j)
// lexicographic insert (R6 quantization failed absmax).
// ---------------------------------------------------------------------------
__global__ __launch_bounds__(512, 2) void knn64_kernel(
    const float* __restrict__ x, const float* __restrict__ d2,
    int* __restrict__ idx) {
  const int b    = blockIdx.y;
  const int lane = threadIdx.x & 63;
  const int wv_u = __builtin_amdgcn_readfirstlane(threadIdx.x >> 6);  // 0..7
  const int i0   = blockIdx.x * 64;
  const float* xb  = x  + (size_t)b * NPTS * HID;
  const float* d2b = d2 + (size_t)b * NPTS;

  constexpr int NE = 8 * K_NN;                       // 96 merge entries/row
  __shared__ __align__(16) char smem[64 * (NE + 1) * 8];   // 49664 B
  float* xis   = (float*)smem;                       // [64][68] floats, 17.4 KB
  float* lds_d = (float*)smem;                       // [64][97]
  int*   lds_j = (int*)(smem + 64 * (NE + 1) * 4);

  {                                                  // stage xi block, coalesced
    const float4* xg = (const float4*)(xb + (size_t)i0 * HID);
    for (int t = threadIdx.x; t < 64 * 16; t += 512) {
      int r = t >> 4, q = t & 15;
      *(float4*)&xis[r * 68 + 4 * q] = xg[r * 16 + q];
    }
  }
  __syncthreads();

  float bd[K_NN]; int bj[K_NN];
#pragma unroll
  for (int k = 0; k < K_NN; ++k) { bd[k] = 3.4e38f; bj[k] = 0x7fffffff; }

  const int j0 = wv_u * 128;                         // uniform slice base
#pragma unroll 1
  for (int jt = 0; jt < 128; jt += 8) {              // 8-j tiles
    v2f acc[8];
#pragma unroll
    for (int t = 0; t < 8; ++t) acc[t] = v2f{0.f, 0.f};

#pragma unroll 1
    for (int half = 0; half < 2; ++half) {           // halves NOT coexistent
      v2f xi2[16];                                   // 32 VGPR transient
      const float4* xr = (const float4*)&xis[lane * 68 + half * 32];
#pragma unroll
      for (int q = 0; q < 8; ++q) {
        float4 v = xr[q];
        xi2[2 * q + 0] = v2f{v.x, v.y};
        xi2[2 * q + 1] = v2f{v.z, v.w};
      }
#pragma unroll
      for (int t = 0; t < 8; ++t) {
        const v2f* xj2 = (const v2f*)(xb + (size_t)(j0 + jt + t) * HID + half * 32);
#pragma unroll
        for (int q = 0; q < 16; ++q)                 // uniform xj -> s_load
          acc[t] = __builtin_elementwise_fma(xi2[q], xj2[q], acc[t]);
      }
    }

#pragma unroll
    for (int t = 0; t < 8; ++t) {                    // epilogue per j
      const int j = j0 + jt + t;
      const float dot = acc[t].x + acc[t].y;
      // d2_i (row-constant) dropped: doesn't change per-row top-k order.
      const float dval = fmaf(-2.f, dot, d2b[j]);
      if (dval < bd[K_NN - 1]) {                     // strict <: scanning j
        float dk = dval; int jk = j;                 // ascending keeps lower j
#pragma unroll
        for (int s = 0; s < K_NN; ++s) {             // exact branchless insert
          bool sw = dk < bd[s];
          float nd = fminf(dk, bd[s]);
          float xd = fmaxf(dk, bd[s]);
          int nj = sw ? jk : bj[s];
          int xjj = sw ? bj[s] : jk;
          bd[s] = nd; bj[s] = nj; dk = xd; jk = xjj;
        }
      }
    }
  }

  __syncthreads();                                   // xis reads done (aliasing)
#pragma unroll
  for (int k = 0; k < K_NN; ++k) {
    lds_d[lane * (NE + 1) + wv_u * K_NN + k] = bd[k];
    lds_j[lane * (NE + 1) + wv_u * K_NN + k] = bj[k];
  }
  __syncthreads();

  if (wv_u == 0) {                                   // merge 8 sorted slices
    float md[K_NN]; int mj[K_NN];
#pragma unroll
    for (int k = 0; k < K_NN; ++k) { md[k] = 3.4e38f; mj[k] = 0x7fffffff; }
    for (int e = 0; e < NE; ++e) {                   // ascending slice order
      float dk = lds_d[lane * (NE + 1) + e];
      int jk = lds_j[lane * (NE + 1) + e];
      if (dk < md[K_NN - 1]) {
#pragma unroll
        for (int s = 0; s < K_NN; ++s) {
          bool sw = dk < md[s];
          float nd = fminf(dk, md[s]);
          float xd = fmaxf(dk, md[s]);
          int nj = sw ? jk : mj[s];
          int xjj = sw ? mj[s] : jk;
          md[s] = nd; mj[s] = nj; dk = xd; jk = xjj;
        }
      }
    }
    int* op = idx + ((size_t)b * NPTS + i0 + lane) * K_NN;
#pragma unroll
    for (int k = 0; k < K_NN; ++k) op[k] = mj[k];
  }
}

// ---------------------------------------------------------------------------
// kNN C=3 (layer 0): xi[3] in registers, R9 shape (proven).
// ---------------------------------------------------------------------------
__global__ __launch_bounds__(512, 2) void knn3_kernel(
    const float* __restrict__ x, const float* __restrict__ d2,
    int* __restrict__ idx) {
  const int b    = blockIdx.y;
  const int lane = threadIdx.x & 63;
  const int wv_u = __builtin_amdgcn_readfirstlane(threadIdx.x >> 6);  // 0..7
  const int i    = blockIdx.x * 64 + lane;
  const float* xb  = x  + (size_t)b * NPTS * 3;
  const float* d2b = d2 + (size_t)b * NPTS;

  constexpr int NE = 8 * K_NN;
  __shared__ float lds_d[64][NE + 1];
  __shared__ int   lds_j[64][NE + 1];

  float xi0 = xb[(size_t)i * 3 + 0];
  float xi1 = xb[(size_t)i * 3 + 1];
  float xi2v = xb[(size_t)i * 3 + 2];

  float bd[K_NN]; int bj[K_NN];
#pragma unroll
  for (int k = 0; k < K_NN; ++k) { bd[k] = 3.4e38f; bj[k] = 0x7fffffff; }

  const int j0 = wv_u * 128;
#pragma unroll 2
  for (int jj = 0; jj < 128; ++jj) {
    const int j = j0 + jj;                           // uniform
    const float* xj = xb + (size_t)j * 3;            // uniform -> s_load
    const float d2j = d2b[j];
    float dot = fmaf(xi0, xj[0], 0.f);
    dot = fmaf(xi1, xj[1], dot);
    dot = fmaf(xi2v, xj[2], dot);
    const float dval = fmaf(-2.f, dot, d2j);
    if (dval < bd[K_NN - 1]) {
      float dk = dval; int jk = j;
#pragma unroll
      for (int s = 0; s < K_NN; ++s) {
        bool sw = dk < bd[s];
        float nd = fminf(dk, bd[s]);
        float xd = fmaxf(dk, bd[s]);
        int nj = sw ? jk : bj[s];
        int xjj = sw ? bj[s] : jk;
        bd[s] = nd; bj[s] = nj; dk = xd; jk = xjj;
      }
    }
  }

#pragma unroll
  for (int k = 0; k < K_NN; ++k) {
    lds_d[lane][wv_u * K_NN + k] = bd[k];
    lds_j[lane][wv_u * K_NN + k] = bj[k];
  }
  __syncthreads();

  if (wv_u == 0) {
    float md[K_NN]; int mj[K_NN];
#pragma unroll
    for (int k = 0; k < K_NN; ++k) { md[k] = 3.4e38f; mj[k] = 0x7fffffff; }
    for (int e = 0; e < NE; ++e) {
      float dk = lds_d[lane][e]; int jk = lds_j[lane][e];
      if (dk < md[K_NN - 1]) {
#pragma unroll
        for (int s = 0; s < K_NN; ++s) {
          bool sw = dk < md[s];
          float nd = fminf(dk, md[s]);
          float xd = fmaxf(dk, md[s]);
          int nj = sw ? jk : mj[s];
          int xjj = sw ? mj[s] : jk;
          md[s] = nd; mj[s] = nj; dk = xd; jk = xjj;
        }
      }
    }
    int* op = idx + ((size_t)b * NPTS + blockIdx.x * 64 + lane) * K_NN;
#pragma unroll
    for (int k = 0; k < K_NN; ++k) op[k] = mj[k];
  }
}

// ---------------------------------------------------------------------------
// wprep: W1c = W1a - W1b for all 4 layers.
// ---------------------------------------------------------------------------
__global__ __launch_bounds__(256) void wprep_kernel(const float* __restrict__ wa,
                                                    const float* __restrict__ w0a,
                                                    float* __restrict__ w1c) {
  int t = blockIdx.x * 256 + threadIdx.x;
  if (t < 12288) {
    int i = t >> 12, r = t & 4095;
    w1c[t] = wa[i * 8192 + r] - wa[i * 8192 + 4096 + r];
  } else if (t < 12288 + 192) {
    int r = t - 12288;
    w1c[t] = w0a[r] - w0a[192 + r];
  }
}

// ---------------------------------------------------------------------------
// rowgemm2: dual-output 64x64 rowgemm. YA = biasA + X@WA, YB = X@WB.
// ---------------------------------------------------------------------------
__global__ __launch_bounds__(256) void rowgemm2_kernel(
    const float* __restrict__ X, const float* __restrict__ WA,
    const float* __restrict__ biasA, const float* __restrict__ WB,
    float* __restrict__ YA, float* __restrict__ YB) {
  __shared__ float wsa[HID * HID];
  __shared__ float wsb[HID * HID];
  for (int t = threadIdx.x; t < HID * HID; t += 256) { wsa[t] = WA[t]; wsb[t] = WB[t]; }
  __syncthreads();

  const int lane = threadIdx.x & 63;
  const int wv   = threadIdx.x >> 6;
  const int fq   = lane & 15;
  const int rg   = lane >> 4;
  const int r0   = blockIdx.x * 32 + wv * 8 + rg * 2;

  const float4* X4 = (const float4*)X;
  const float4* WA4 = (const float4*)wsa;
  const float4* WB4 = (const float4*)wsb;
  float aA0[4] = {0,0,0,0}, aA1[4] = {0,0,0,0};
  float aB0[4] = {0,0,0,0}, aB1[4] = {0,0,0,0};

#pragma unroll 2
  for (int cq = 0; cq < 16; ++cq) {
    float4 xa = X4[(size_t)r0 * 16 + cq];
    float4 xb_ = X4[(size_t)(r0 + 1) * 16 + cq];
    float ea[4] = {xa.x, xa.y, xa.z, xa.w};
    float eb[4] = {xb_.x, xb_.y, xb_.z, xb_.w};
#pragma unroll
    for (int d = 0; d < 4; ++d) {
      float4 wa4 = WA4[(cq * 4 + d) * 16 + fq];
      float4 wb4 = WB4[(cq * 4 + d) * 16 + fq];
      float wA[4] = {wa4.x, wa4.y, wa4.z, wa4.w};
      float wB[4] = {wb4.x, wb4.y, wb4.z, wb4.w};
#pragma unroll
      for (int k = 0; k < 4; ++k) {
        aA0[k] = fmaf(ea[d], wA[k], aA0[k]);
        aA1[k] = fmaf(eb[d], wA[k], aA1[k]);
        aB0[k] = fmaf(ea[d], wB[k], aB0[k]);
        aB1[k] = fmaf(eb[d], wB[k], aB1[k]);
      }
    }
  }
  float4 b4 = ((const float4*)biasA)[fq];
  float4 oA0{aA0[0] + b4.x, aA0[1] + b4.y, aA0[2] + b4.z, aA0[3] + b4.w};
  float4 oA1{aA1[0] + b4.x, aA1[1] + b4.y, aA1[2] + b4.z, aA1[3] + b4.w};
  float4 oB0{aB0[0], aB0[1], aB0[2], aB0[3]};
  float4 oB1{aB1[0], aB1[1], aB1[2], aB1[3]};
  ((float4*)YA)[(size_t)r0 * 16 + fq] = oA0;
  ((float4*)YA)[(size_t)(r0 + 1) * 16 + fq] = oA1;
  ((float4*)YB)[(size_t)r0 * 16 + fq] = oB0;
  ((float4*)YB)[(size_t)(r0 + 1) * 16 + fq] = oB1;
}

// ---------------------------------------------------------------------------
// dual3: layer-0 projections (C=3). hxi = x@(A-B) + b1, hxj = x@B.
// ---------------------------------------------------------------------------
__global__ __launch_bounds__(256) void dual3_kernel(
    const float* __restrict__ x, const float* __restrict__ w1c0,
    const float* __restrict__ w0a, const float* __restrict__ b1,
    float* __restrict__ hxi, float* __restrict__ hxj) {
  __shared__ float Cs[3 * HID], Bs[3 * HID], bs[HID];
  for (int t = threadIdx.x; t < 3 * HID; t += 256) {
    Cs[t] = w1c0[t];
    Bs[t] = w0a[192 + t];
  }
  if (threadIdx.x < HID) bs[threadIdx.x] = b1[threadIdx.x];
  __syncthreads();

  const int lane = threadIdx.x & 63;
  const int wv   = __builtin_amdgcn_readfirstlane(threadIdx.x >> 6);
  const int node0 = blockIdx.x * 32;
#pragma unroll 1
  for (int it = 0; it < 8; ++it) {
    const int n = node0 + it * 4 + wv;               // uniform
    const float* xr = x + (size_t)n * 3;             // uniform -> s_load
    float x0 = xr[0], x1 = xr[1], x2 = xr[2];
    float hi = bs[lane];
    hi = fmaf(x0, Cs[0 * HID + lane], hi);
    hi = fmaf(x1, Cs[1 * HID + lane], hi);
    hi = fmaf(x2, Cs[2 * HID + lane], hi);
    float hj = x0 * Bs[0 * HID + lane];
    hj = fmaf(x1, Bs[1 * HID + lane], hj);
    hj = fmaf(x2, Bs[2 * HID + lane], hj);
    hxi[(size_t)n * HID + lane] = hi;
    hxj[(size_t)n * HID + lane] = hj;
  }
}

// ---------------------------------------------------------------------------
// egstats: BN sum/sumsq over all edges of h = hxi[n] + hxj[j].
// v11: 2 nodes per iteration (26 gathers in flight) to hide L2 latency.
// ---------------------------------------------------------------------------
__global__ __launch_bounds__(256) void egstats_kernel(
    const int* __restrict__ idx, const float* __restrict__ hxi,
    const float* __restrict__ hxj, float* __restrict__ partial) {
  const int lane = threadIdx.x & 63;
  const int wv   = __builtin_amdgcn_readfirstlane(threadIdx.x >> 6);
  const int node0 = blockIdx.x * 32;
  float s1 = 0.f, s2 = 0.f;

#pragma unroll 1
  for (int it = 0; it < 4; ++it) {
    const int n0 = node0 + it * 8 + wv;              // uniform
    const int n1 = n0 + 4;                           // uniform
    const int bbase = (n0 >> 10) << 10;              // b*N (same for n1)
    const int* ip0 = idx + (size_t)n0 * K_NN;        // uniform -> s_load
    const int* ip1 = idx + (size_t)n1 * K_NN;
    int j0[K_NN], j1[K_NN];
#pragma unroll
    for (int k = 0; k < K_NN; ++k) { j0[k] = ip0[k]; j1[k] = ip1[k]; }
    const float hv0 = hxi[(size_t)n0 * HID + lane];
    const float hv1 = hxi[(size_t)n1 * HID + lane];
    float v0[K_NN], v1[K_NN];
#pragma unroll
    for (int k = 0; k < K_NN; ++k) {                 // 24 independent gathers
      v0[k] = hxj[(size_t)(bbase + j0[k]) * HID + lane];
      v1[k] = hxj[(size_t)(bbase + j1[k]) * HID + lane];
    }
#pragma unroll
    for (int k = 0; k < K_NN; ++k) {
      float h0 = hv0 + v0[k], h1 = hv1 + v1[k];
      s1 += h0 + h1;
      s2 = fmaf(h0, h0, s2); s2 = fmaf(h1, h1, s2);
    }
  }

  __shared__ float red[4][HID];
  red[wv][lane] = s1;
  __syncthreads();
  if (threadIdx.x < HID)
    partial[(size_t)blockIdx.x * 128 + lane] =
        (red[0][lane] + red[1][lane]) + (red[2][lane] + red[3][lane]);
  __syncthreads();
  red[wv][lane] = s2;
  __syncthreads();
  if (threadIdx.x < HID)
    partial[(size_t)blockIdx.x * 128 + 64 + lane] =
        (red[0][lane] + red[1][lane]) + (red[2][lane] + red[3][lane]);
}

// ---------------------------------------------------------------------------
// Reduce 1024 block-partials, finalize BN scale/shift into stats[128..255].
// ---------------------------------------------------------------------------
__global__ void bn_reduce_finalize_kernel(const float* __restrict__ g,
                                          const float* __restrict__ be,
                                          const float* __restrict__ partial,
                                          float* __restrict__ stats) {
  int t = threadIdx.x;                               // 0..127
  float a0 = 0.f, a1 = 0.f, a2 = 0.f, a3 = 0.f;
  for (int gb = 0; gb < 1024; gb += 4) {
    a0 += partial[(size_t)(gb + 0) * 128 + t];
    a1 += partial[(size_t)(gb + 1) * 128 + t];
    a2 += partial[(size_t)(gb + 2) * 128 + t];
    a3 += partial[(size_t)(gb + 3) * 128 + t];
  }
  __shared__ float sm[128];
  sm[t] = (a0 + a1) + (a2 + a3);
  __syncthreads();
  if (t < HID) {
    const float inv_n = 1.f / (float)(BATCH * NPTS * K_NN);
    float m = sm[t] * inv_n;
    float v = sm[HID + t] * inv_n - m * m;
    float A = g[t] * rsqrtf(v + BN_EPS);
    stats[128 + t] = A;
    stats[192 + t] = be[t] - m * A;
  }
}

// ---------------------------------------------------------------------------
// egapply_gemm: fused BN-apply + relu + mean-over-K + W2 + b2.
// v11: 2 nodes per iteration for gather-latency hiding.
// ---------------------------------------------------------------------------
__global__ __launch_bounds__(256) void egapply_gemm_kernel(
    const int* __restrict__ idx, const float* __restrict__ hxi,
    const float* __restrict__ hxj, const float* __restrict__ stats,
    const float* __restrict__ W2, const float* __restrict__ b2,
    float* __restrict__ out) {
  __shared__ float w2s[HID * HID];
  __shared__ float red[32][HID];
  for (int t = threadIdx.x; t < HID * HID; t += 256) w2s[t] = W2[t];

  const int lane = threadIdx.x & 63;
  const int wv   = __builtin_amdgcn_readfirstlane(threadIdx.x >> 6);
  const int node0 = blockIdx.x * 32;
  const float A = stats[128 + lane], Bc = stats[192 + lane];

#pragma unroll 1
  for (int it = 0; it < 4; ++it) {
    const int n0 = node0 + it * 8 + wv;              // uniform
    const int n1 = n0 + 4;
    const int bbase = (n0 >> 10) << 10;
    const int* ip0 = idx + (size_t)n0 * K_NN;        // uniform -> s_load
    const int* ip1 = idx + (size_t)n1 * K_NN;
    int j0[K_NN], j1[K_NN];
#pragma unroll
    for (int k = 0; k < K_NN; ++k) { j0[k] = ip0[k]; j1[k] = ip1[k]; }
    const float hv0 = hxi[(size_t)n0 * HID + lane];
    const float hv1 = hxi[(size_t)n1 * HID + lane];
    float v0[K_NN], v1[K_NN];
#pragma unroll
    for (int k = 0; k < K_NN; ++k) {
      v0[k] = hxj[(size_t)(bbase + j0[k]) * HID + lane];
      v1[k] = hxj[(size_t)(bbase + j1[k]) * HID + lane];
    }
    float a0 = 0.f, a1 = 0.f;
#pragma unroll
    for (int k = 0; k < K_NN; ++k) {
      a0 += fmaxf(fmaf(A, hv0 + v0[k], Bc), 0.f);
      a1 += fmaxf(fmaf(A, hv1 + v1[k], Bc), 0.f);
    }
    red[it * 8 + wv][lane] = a0;
    red[it * 8 + 4 + wv][lane] = a1;
  }
  __syncthreads();

  const float b2f = b2[lane];
  const float inv = 1.f / (float)K_NN;
#pragma unroll 2
  for (int p = 0; p < 8; ++p) {
    int r = p * 4 + wv;                              // uniform row
    float acc = 0.f;
#pragma unroll 8
    for (int h = 0; h < HID; ++h) acc = fmaf(red[r][h], w2s[h * HID + lane], acc);
    out[(size_t)(node0 + r) * HID + lane] = fmaf(acc, inv, b2f);
  }
}

// ---------------------------------------------------------------------------
__global__ __launch_bounds__(256) void pool_kernel(const float* __restrict__ h,
                                                   float* __restrict__ pooled) {
  const int b = blockIdx.x;
  const int f = threadIdx.x & 63;
  const int gsz = threadIdx.x >> 6;
  __shared__ float red[4][HID];
  float s = 0.f;
  for (int n = gsz; n < NPTS; n += 4) s += h[((size_t)b * NPTS + n) * HID + f];
  red[gsz][f] = s;
  __syncthreads();
  if (threadIdx.x < HID)
    pooled[b * HID + f] = ((red[0][f] + red[1][f]) + (red[2][f] + red[3][f])) * (1.f / (float)NPTS);
}

__global__ __launch_bounds__(256) void head_kernel(const float* __restrict__ pooled,
    const float* __restrict__ wf1, const float* __restrict__ bf1,
    const float* __restrict__ gf, const float* __restrict__ bef,
    const float* __restrict__ wf2, const float* __restrict__ bf2,
    float* __restrict__ out) {
  __shared__ float pl[BATCH * HID];
  __shared__ float t[BATCH * 32];
  __shared__ float Ab[32], Bb[32];
  for (int i = threadIdx.x; i < BATCH * HID; i += 256) pl[i] = pooled[i];
  __syncthreads();
  for (int i = threadIdx.x; i < BATCH * 32; i += 256) {
    int s = i >> 5, f1 = i & 31;
    float acc = bf1[f1];
    for (int h = 0; h < HID; ++h) acc = fmaf(pl[s * HID + h], wf1[h * 32 + f1], acc);
    t[i] = acc;
  }
  __syncthreads();
  if (threadIdx.x < 32) {
    int f1 = threadIdx.x;
    float m = 0.f;
    for (int s = 0; s < BATCH; ++s) m += t[s * 32 + f1];
    m *= (1.f / (float)BATCH);
    float v = 0.f;
    for (int s = 0; s < BATCH; ++s) { float d = t[s * 32 + f1] - m; v = fmaf(d, d, v); }
    v *= (1.f / (float)BATCH);
    float A = gf[f1] * rsqrtf(v + BN_EPS);
    Ab[f1] = A; Bb[f1] = bef[f1] - m * A;
  }
  __syncthreads();
  for (int i = threadIdx.x; i < BATCH * 32; i += 256) {
    int f1 = i & 31;
    t[i] = fmaxf(fmaf(Ab[f1], t[i], Bb[f1]), 0.f);
  }
  __syncthreads();
  if (threadIdx.x < BATCH * 2) {
    int s = threadIdx.x >> 1, o = threadIdx.x & 1;
    float acc = bf2[o];
    for (int f1 = 0; f1 < 32; ++f1) acc = fmaf(t[s * 32 + f1], wf2[f1 * 2 + o], acc);
    out[s * 2 + o] = acc;
  }
}

// ---------------------------------------------------------------------------
extern "C" void kernel_launch(void* const* d_in, const int* in_sizes, int n_in,
                              void* d_out, int out_size, void* d_ws, size_t ws_size,
                              hipStream_t stream) {
  const float* x   = (const float*)d_in[0];
  const float* w0a = (const float*)d_in[1];
  const float* b0a = (const float*)d_in[2];
  const float* g0  = (const float*)d_in[3];
  const float* be0 = (const float*)d_in[4];
  const float* w0b = (const float*)d_in[5];
  const float* b0b = (const float*)d_in[6];
  const float* wa  = (const float*)d_in[7];
  const float* ba  = (const float*)d_in[8];
  const float* ga  = (const float*)d_in[9];
  const float* bea = (const float*)d_in[10];
  const float* wb  = (const float*)d_in[11];
  const float* bb  = (const float*)d_in[12];
  const float* wf1 = (const float*)d_in[13];
  const float* bf1 = (const float*)d_in[14];
  const float* gf  = (const float*)d_in[15];
  const float* bef = (const float*)d_in[16];
  const float* wf2 = (const float*)d_in[17];
  const float* bf2 = (const float*)d_in[18];

  float* ws = (float*)d_ws;
  const size_t HN = (size_t)BATCH * NPTS * HID;         // 2,097,152
  const size_t ROWS = (size_t)BATCH * NPTS;             // 32768
  float* bufA    = ws;                                  // HN
  float* bufB    = bufA + HN;                           // HN
  float* hxi     = bufB + HN;                           // HN
  float* hxjb    = hxi + HN;                            // HN
  float* w1c     = hxjb + HN;                           // 12544
  int*   idxb    = (int*)(w1c + 12544);                 // ROWS*12
  float* d2buf   = (float*)(idxb + ROWS * K_NN);        // ROWS
  float* stats   = d2buf + ROWS;                        // 256
  float* partial = stats + 256;                         // 1024*128
  float* pooled  = partial + 1024 * 128;                // 2048
  // total ~34 MB of workspace

  wprep_kernel<<<49, 256, 0, stream>>>(wa, w0a, w1c);

  // ---- layer 0 (C=3, gather path) ----
  d2_kernel<3><<<(int)(ROWS / 256), 256, 0, stream>>>(x, d2buf);
  knn3_kernel<<<dim3(16, BATCH), 512, 0, stream>>>(x, d2buf, idxb);
  dual3_kernel<<<1024, 256, 0, stream>>>(x, w1c + 12288, w0a, b0a, hxi, hxjb);
  egstats_kernel<<<1024, 256, 0, stream>>>(idxb, hxi, hxjb, partial);
  bn_reduce_finalize_kernel<<<1, 128, 0, stream>>>(g0, be0, partial, stats);
  egapply_gemm_kernel<<<1024, 256, 0, stream>>>(idxb, hxi, hxjb, stats, w0b, b0b, bufA);

  // ---- layers 1..3 (gather path) ----
  const float* cur = bufA;
  float* nxt = bufB;
  for (int i = 0; i < 3; ++i) {
    const float* W1b = wa + (size_t)i * 8192 + 4096;
    d2_kernel<HID><<<(int)(ROWS / 256), 256, 0, stream>>>(cur, d2buf);
    knn64_kernel<<<dim3(16, BATCH), 512, 0, stream>>>(cur, d2buf, idxb);
    rowgemm2_kernel<<<(int)(ROWS / 32), 256, 0, stream>>>(cur, w1c + (size_t)i * 4096,
                                                          ba + i * HID, W1b, hxi, hxjb);
    egstats_kernel<<<1024, 256, 0, stream>>>(idxb, hxi, hxjb, partial);
    bn_reduce_finalize_kernel<<<1, 128, 0, stream>>>(ga + i * HID, bea + i * HID, partial, stats);
    egapply_gemm_kernel<<<1024, 256, 0, stream>>>(idxb, hxi, hxjb, stats,
                                                  wb + (size_t)i * 4096, bb + i * HID, nxt);
    const float* t = cur; cur = nxt; nxt = (float*)t;
  }

  pool_kernel<<<BATCH, 256, 0, stream>>>(cur, pooled);
  head_kernel<<<1, 256, 0, stream>>>(pooled, wf1, bf1, gf, bef, wf2, bf2, (float*)d_out);
}